// Round 3
// baseline (241.443 us; speedup 1.0000x reference)
//
#include <hip/hip_runtime.h>
#include <cstdint>
#include <cstddef>

#define B_ 8
#define T_ 4096
#define C_ 256
#define NC_ 128
#define L_ (T_ / NC_)   // 32 steps per chunk
#define M_ (B_ * T_)    // 32768 rows

typedef float f32x4 __attribute__((ext_vector_type(4)));
typedef short bf16x8 __attribute__((ext_vector_type(8)));

__device__ __forceinline__ unsigned short f2b(float f) {
    unsigned int u = __float_as_uint(f);
    u += 0x7fffu + ((u >> 16) & 1u);   // round-to-nearest-even
    return (unsigned short)(u >> 16);
}
__device__ __forceinline__ float b2f(unsigned short h) {
    return __uint_as_float(((unsigned int)h) << 16);
}

// ---------------- f32 -> bf16 weight converts (4 x 256x256, tiny) -------------
__global__ __launch_bounds__(256) void cvt_w(const float* __restrict__ w0, const float* __restrict__ w1,
                                             const float* __restrict__ w2, const float* __restrict__ w3,
                                             unsigned short* __restrict__ o0, unsigned short* __restrict__ o1,
                                             unsigned short* __restrict__ o2, unsigned short* __restrict__ o3) {
    const float* in; unsigned short* out;
    switch (blockIdx.y) {
        case 0: in = w0; out = o0; break;
        case 1: in = w1; out = o1; break;
        case 2: in = w2; out = o2; break;
        default: in = w3; out = o3; break;
    }
    size_t i = ((size_t)blockIdx.x * 256 + threadIdx.x) * 4;
    float4 v = *(const float4*)(in + i);
    *(ushort4*)(out + i) = make_ushort4(f2b(v.x), f2b(v.y), f2b(v.z), f2b(v.w));
}

// ---------------- x f32 -> bf16 (8 elems/thread) ------------------------------
__global__ __launch_bounds__(256) void cvt_x(const float* __restrict__ in,
                                             unsigned short* __restrict__ out) {
    size_t i = ((size_t)blockIdx.x * 256 + threadIdx.x) * 8;
    float4 a = *(const float4*)(in + i);
    float4 b = *(const float4*)(in + i + 4);
    bf16x8 o;
    o[0] = (short)f2b(a.x); o[1] = (short)f2b(a.y);
    o[2] = (short)f2b(a.z); o[3] = (short)f2b(a.w);
    o[4] = (short)f2b(b.x); o[5] = (short)f2b(b.y);
    o[6] = (short)f2b(b.z); o[7] = (short)f2b(b.w);
    *(bf16x8*)(out + i) = o;
}

// ---------------- Tiled GEMM: O[m,n] = sum_k A[m,k] * W[n,k] ------------------
// Wave: 16*MT rows x 128 cols. Block: 4 waves = 64*MT rows x 128 cols.
// grid = (M/(64*MT), 2 col-halves, n_mats). mat 0 -> f0 (f32), mat 1 -> f1
// (f32), mat 2 -> b2 (sigmoid, bf16).
// A-frag (16x16x32): A[m = lane&15][k = (lane>>4)*8 + j]
// B-frag:            W rows (n = lane&15, k = (lane>>4)*8 + j)
// D:                 D[row = (lane>>4)*4 + i][col = lane&15]
template <int MT>
__global__ __launch_bounds__(256) void gemm_tile(const unsigned short* __restrict__ A,
                                                 const unsigned short* __restrict__ w0,
                                                 const unsigned short* __restrict__ w1,
                                                 const unsigned short* __restrict__ w2,
                                                 float* __restrict__ f0,
                                                 float* __restrict__ f1,
                                                 unsigned short* __restrict__ b2) {
    const int wave = threadIdx.x >> 6, lane = threadIdx.x & 63;
    const int quad = lane >> 4, l16 = lane & 15;
    const int m0 = blockIdx.x * (64 * MT) + wave * (16 * MT);
    const int n0 = blockIdx.y * 128;
    const int mat = blockIdx.z;
    const unsigned short* W = (mat == 0) ? w0 : (mat == 1) ? w1 : w2;

    bf16x8 af[MT][8];
#pragma unroll
    for (int mt = 0; mt < MT; ++mt) {
        const unsigned short* Ar = A + (size_t)(m0 + mt * 16 + l16) * C_ + quad * 8;
#pragma unroll
        for (int kc = 0; kc < 8; ++kc) af[mt][kc] = *(const bf16x8*)(Ar + kc * 32);
    }

#pragma unroll
    for (int nt = 0; nt < 8; ++nt) {
        const unsigned short* Wrow = W + (size_t)(n0 + nt * 16 + l16) * C_ + quad * 8;
        f32x4 acc[MT];
#pragma unroll
        for (int mt = 0; mt < MT; ++mt) acc[mt] = (f32x4){0.f, 0.f, 0.f, 0.f};
#pragma unroll
        for (int kc = 0; kc < 8; ++kc) {
            bf16x8 bf = *(const bf16x8*)(Wrow + kc * 32);
#pragma unroll
            for (int mt = 0; mt < MT; ++mt)
                acc[mt] = __builtin_amdgcn_mfma_f32_16x16x32_bf16(af[mt][kc], bf, acc[mt], 0, 0, 0);
        }
        const int col = n0 + nt * 16 + l16;
#pragma unroll
        for (int mt = 0; mt < MT; ++mt) {
#pragma unroll
            for (int i = 0; i < 4; ++i) {
                const int row = m0 + mt * 16 + quad * 4 + i;
                if (mat == 0) {
                    f0[(size_t)row * C_ + col] = acc[mt][i];
                } else if (mat == 1) {
                    f1[(size_t)row * C_ + col] = acc[mt][i];
                } else {
                    float s = 1.f / (1.f + __expf(-acc[mt][i]));
                    b2[(size_t)row * C_ + col] = f2b(s);
                }
            }
        }
    }
}

// ---------------- WKV pass 1: chunk-local states from zero init ----------------
__global__ __launch_bounds__(256) void wkv_pass1(const float* __restrict__ k,
                                                 const float* __restrict__ v,
                                                 const float* __restrict__ decay,
                                                 float* __restrict__ sp, float* __restrict__ sq,
                                                 float* __restrict__ so) {
    const int c = threadIdx.x, chunk = blockIdx.x, b = blockIdx.y;
    const float w = decay[c] * (1.0f / T_);
    size_t base = ((size_t)b * T_ + (size_t)chunk * L_) * C_ + c;
    float p = 0.f, q = 0.f, o = -1e38f;
    for (int t = 0; t < L_; t += 8) {
        float kk[8], vv[8];
#pragma unroll
        for (int j = 0; j < 8; ++j) {
            kk[j] = k[base + (size_t)(t + j) * C_];
            vv[j] = v[base + (size_t)(t + j) * C_];
        }
#pragma unroll
        for (int j = 0; j < 8; ++j) {
            float wo = w + o;
            float no = fmaxf(wo, kk[j]);
            float a2 = __expf(wo - no), b2 = __expf(kk[j] - no);
            p = a2 * p + b2 * vv[j];
            q = a2 * q + b2;
            o = no;
        }
    }
    size_t idx = ((size_t)b * NC_ + chunk) * C_ + c;
    sp[idx] = p; sq[idx] = q; so[idx] = o;
}

// ---------------- WKV combine: sequential over chunks, emit init states --------
__global__ __launch_bounds__(256) void wkv_combine(const float* __restrict__ decay,
                                                   const float* __restrict__ sp,
                                                   const float* __restrict__ sq,
                                                   const float* __restrict__ so,
                                                   float* __restrict__ pi, float* __restrict__ qi,
                                                   float* __restrict__ oi) {
    const int c = threadIdx.x, b = blockIdx.x;
    const float wL = decay[c] * (1.0f / T_) * (float)L_;
    float p = 0.f, q = 0.f, o = -1e38f;
    for (int ch = 0; ch < NC_; ch += 8) {
        float lp[8], lq[8], lo[8];
#pragma unroll
        for (int j = 0; j < 8; ++j) {
            size_t idx = ((size_t)b * NC_ + ch + j) * C_ + c;
            lp[j] = sp[idx]; lq[j] = sq[idx]; lo[j] = so[idx];
        }
#pragma unroll
        for (int j = 0; j < 8; ++j) {
            size_t idx = ((size_t)b * NC_ + ch + j) * C_ + c;
            pi[idx] = p; qi[idx] = q; oi[idx] = o;   // state BEFORE this chunk
            float ow = o + wL;
            float no = fmaxf(ow, lo[j]);
            float ea = __expf(ow - no), eb = __expf(lo[j] - no);
            p = ea * p + eb * lp[j];
            q = ea * q + eb * lq[j];
            o = no;
        }
    }
}

// ---------------- WKV pass 2 fused with LayerNorm + sigmoid gate ---------------
// Block = (chunk, b), 256 threads = one channel each. Block owns all 256
// channels of L_ consecutive timesteps -> LayerNorm via LDS transpose.
__global__ __launch_bounds__(256) void wkv_pass2_ln(const float* __restrict__ k,
                                                    const float* __restrict__ v,
                                                    const unsigned short* __restrict__ sr,
                                                    const float* __restrict__ decay,
                                                    const float* __restrict__ first,
                                                    const float* __restrict__ lw,
                                                    const float* __restrict__ lb,
                                                    const float* __restrict__ pi,
                                                    const float* __restrict__ qi,
                                                    const float* __restrict__ oi,
                                                    unsigned short* __restrict__ z) {
    __shared__ float tile[8][260];
    __shared__ float mu_s[8], rs_s[8];
    const int c = threadIdx.x, chunk = blockIdx.x, b = blockIdx.y;
    const int wave = c >> 6, lane = c & 63;
    const float w = decay[c] * (1.0f / T_);
    const float u = first[c] * (1.0f / T_);
    const float gw = lw[c], gb = lb[c];
    size_t sidx = ((size_t)b * NC_ + chunk) * C_ + c;
    float p = pi[sidx], q = qi[sidx], o = oi[sidx];
    size_t base = ((size_t)b * T_ + (size_t)chunk * L_) * C_ + c;

    for (int t = 0; t < L_; t += 8) {
        float kk[8], vv[8], yy[8];
#pragma unroll
        for (int j = 0; j < 8; ++j) {
            kk[j] = k[base + (size_t)(t + j) * C_];
            vv[j] = v[base + (size_t)(t + j) * C_];
        }
#pragma unroll
        for (int j = 0; j < 8; ++j) {
            float uk = u + kk[j];
            float no = fmaxf(o, uk);
            float a = __expf(o - no), bb = __expf(uk - no);
            yy[j] = (a * p + bb * vv[j]) / (a * q + bb);
            float wo = w + o;
            float no2 = fmaxf(wo, kk[j]);
            float a2 = __expf(wo - no2), b2 = __expf(kk[j] - no2);
            p = a2 * p + b2 * vv[j];
            q = a2 * q + b2;
            o = no2;
        }
        __syncthreads();
#pragma unroll
        for (int j = 0; j < 8; ++j) tile[j][c] = yy[j];
        __syncthreads();
#pragma unroll
        for (int r = 0; r < 2; ++r) {
            const int j = wave * 2 + r;
            float4 t4 = *(const float4*)&tile[j][lane * 4];
            float s = t4.x + t4.y + t4.z + t4.w;
            float ss = t4.x * t4.x + t4.y * t4.y + t4.z * t4.z + t4.w * t4.w;
#pragma unroll
            for (int m = 1; m < 64; m <<= 1) {
                s += __shfl_xor(s, m, 64);
                ss += __shfl_xor(ss, m, 64);
            }
            if (lane == 0) {
                float mu = s * (1.f / C_);
                mu_s[j] = mu;
                rs_s[j] = rsqrtf(ss * (1.f / C_) - mu * mu + 1e-5f);
            }
        }
        __syncthreads();
#pragma unroll
        for (int j = 0; j < 8; ++j) {
            float zz = (yy[j] - mu_s[j]) * rs_s[j] * gw + gb;
            zz *= b2f(sr[base + (size_t)(t + j) * C_]);
            z[base + (size_t)(t + j) * C_] = f2b(zz);
        }
    }
}

extern "C" void kernel_launch(void* const* d_in, const int* in_sizes, int n_in,
                              void* d_out, int out_size, void* d_ws, size_t ws_size,
                              hipStream_t stream) {
    const float* x     = (const float*)d_in[0];
    const float* Wk    = (const float*)d_in[1];
    const float* Wv    = (const float*)d_in[2];
    const float* Wr    = (const float*)d_in[3];
    const float* Wo    = (const float*)d_in[4];
    const float* decay = (const float*)d_in[5];
    const float* first = (const float*)d_in[6];
    const float* lnw   = (const float*)d_in[7];
    const float* lnb   = (const float*)d_in[8];
    float* out = (float*)d_out;

    char* ws = (char*)d_ws;
    const size_t NE = (size_t)M_ * C_;              // 8388608
    unsigned short* wkb = (unsigned short*)ws; ws += 65536 * 2;
    unsigned short* wvb = (unsigned short*)ws; ws += 65536 * 2;
    unsigned short* wrb = (unsigned short*)ws; ws += 65536 * 2;
    unsigned short* wob = (unsigned short*)ws; ws += 65536 * 2;
    unsigned short* xb  = (unsigned short*)ws; ws += NE * 2;
    float* kbuf = (float*)ws; ws += NE * 4;
    float* vbuf = (float*)ws; ws += NE * 4;
    unsigned short* srb = (unsigned short*)ws; ws += NE * 2;
    unsigned short* zb  = (unsigned short*)ws; ws += NE * 2;
    const size_t SE = (size_t)B_ * NC_ * C_;        // 262144
    float* sp = (float*)ws; ws += SE * 4;
    float* sq = (float*)ws; ws += SE * 4;
    float* so = (float*)ws; ws += SE * 4;
    float* pi = (float*)ws; ws += SE * 4;
    float* qi = (float*)ws; ws += SE * 4;
    float* oi = (float*)ws; ws += SE * 4;

    cvt_w<<<dim3(64, 4), 256, 0, stream>>>(Wk, Wv, Wr, Wo, wkb, wvb, wrb, wob);
    cvt_x<<<NE / (256 * 8), 256, 0, stream>>>(x, xb);

    // QKV: 256 row-blocks x 2 col-halves x 3 mats = 1536 blocks
    gemm_tile<2><<<dim3(M_ / 128, 2, 3), 256, 0, stream>>>(xb, wkb, wvb, wrb,
                                                           kbuf, vbuf, srb);

    wkv_pass1<<<dim3(NC_, B_), 256, 0, stream>>>(kbuf, vbuf, decay, sp, sq, so);
    wkv_combine<<<B_, 256, 0, stream>>>(decay, sp, sq, so, pi, qi, oi);
    wkv_pass2_ln<<<dim3(NC_, B_), 256, 0, stream>>>(kbuf, vbuf, srb, decay, first,
                                                    lnw, lnb, pi, qi, oi, zb);

    // Output GEMM: 512 row-blocks x 2 col-halves = 1024 blocks
    gemm_tile<1><<<dim3(M_ / 64, 2, 1), 256, 0, stream>>>(zb, wob, wob, wob,
                                                          out, nullptr, nullptr);
}